// Round 4
// baseline (292.311 us; speedup 1.0000x reference)
//
#include <hip/hip_runtime.h>
#include <hip/hip_bf16.h>

#define N_FEAT 3072
#define LATENT 128
#define LOG2PI 1.8378770664093453f

typedef __attribute__((ext_vector_type(8))) short short8;
typedef __attribute__((ext_vector_type(4))) float f32x4;

__device__ __forceinline__ unsigned short f2bf(float x) {
  unsigned int u = __float_as_uint(x);
  u += 0x7FFFu + ((u >> 16) & 1u);
  return (unsigned short)(u >> 16);
}

// async global->LDS DMA, 16B per lane; lds base must be wave-uniform
#define GLL(g, l)                                                        \
  __builtin_amdgcn_global_load_lds(                                      \
      (__attribute__((address_space(1))) void*)(g),                      \
      (__attribute__((address_space(3))) void*)(l), 16, 0, 0)

// ---------------------------------------------------------------------------
// k_pack: Xb = bf16(x) row-major; ssq[r] = ||x_r||^2; xmu[r] = x_r . mean.
// One wave per row, 4 rows/block, no barriers -- pure streaming.
// ---------------------------------------------------------------------------
__global__ __launch_bounds__(256) void k_pack(const float* __restrict__ ex,
                                              const float* __restrict__ mean,
                                              unsigned short* __restrict__ Xb,
                                              float* __restrict__ ssq,
                                              float* __restrict__ xmu) {
  int w = threadIdx.x >> 6, l = threadIdx.x & 63;
  int row = blockIdx.x * 4 + w;
  const float* xp = ex + (size_t)row * N_FEAT;
  unsigned short* op = Xb + (size_t)row * N_FEAT;
  float sq = 0.f, dm = 0.f;
#pragma unroll
  for (int c = 0; c < 6; ++c) {
    int off = c * 512 + l * 8;
    float4 x0 = *(const float4*)(xp + off);
    float4 x1 = *(const float4*)(xp + off + 4);
    float4 m0 = *(const float4*)(mean + off);
    float4 m1 = *(const float4*)(mean + off + 4);
    sq = fmaf(x0.x, x0.x, sq); sq = fmaf(x0.y, x0.y, sq);
    sq = fmaf(x0.z, x0.z, sq); sq = fmaf(x0.w, x0.w, sq);
    sq = fmaf(x1.x, x1.x, sq); sq = fmaf(x1.y, x1.y, sq);
    sq = fmaf(x1.z, x1.z, sq); sq = fmaf(x1.w, x1.w, sq);
    dm = fmaf(x0.x, m0.x, dm); dm = fmaf(x0.y, m0.y, dm);
    dm = fmaf(x0.z, m0.z, dm); dm = fmaf(x0.w, m0.w, dm);
    dm = fmaf(x1.x, m1.x, dm); dm = fmaf(x1.y, m1.y, dm);
    dm = fmaf(x1.z, m1.z, dm); dm = fmaf(x1.w, m1.w, dm);
    uint4 pk;
    pk.x = (unsigned)f2bf(x0.x) | ((unsigned)f2bf(x0.y) << 16);
    pk.y = (unsigned)f2bf(x0.z) | ((unsigned)f2bf(x0.w) << 16);
    pk.z = (unsigned)f2bf(x1.x) | ((unsigned)f2bf(x1.y) << 16);
    pk.w = (unsigned)f2bf(x1.z) | ((unsigned)f2bf(x1.w) << 16);
    *(uint4*)(op + off) = pk;
  }
#pragma unroll
  for (int o = 1; o < 64; o <<= 1) {
    sq += __shfl_xor(sq, o);
    dm += __shfl_xor(dm, o);
  }
  if (l == 0) {
    ssq[row] = sq;
    xmu[row] = dm;
  }
}

// ---------------------------------------------------------------------------
// k_prep: (a) M += Wchunk^T Wchunk (atomics, M pre-zeroed)
//         (b) Wt[n][k] = bf16(W[k][n])
//         (c) tmu[j] += sum_k W[k][j]*mean[k];  scal[2] += sum mean^2
// 48 blocks x 64 k-rows; W read once.
// ---------------------------------------------------------------------------
#define GR_CHUNK 64
__global__ __launch_bounds__(256) void k_prep(const float* __restrict__ W,
                                              const float* __restrict__ mean,
                                              float* __restrict__ M,
                                              unsigned short* __restrict__ Wt,
                                              float* __restrict__ tmu,
                                              float* __restrict__ scal) {
  __shared__ __align__(16) float Ws[GR_CHUNK * 128];
  int t = threadIdx.x;
  int k0 = blockIdx.x * GR_CHUNK;
  const float* src = W + (size_t)k0 * 128;
#pragma unroll
  for (int c = 0; c < 8; ++c)
    ((float4*)Ws)[t + 256 * c] = ((const float4*)src)[t + 256 * c];
  __syncthreads();
  // gram 8x8 register tiles
  int tr = t >> 4, tc = t & 15;
  float acc[8][8];
#pragma unroll
  for (int r = 0; r < 8; ++r)
#pragma unroll
    for (int c = 0; c < 8; ++c) acc[r][c] = 0.f;
#pragma unroll 2
  for (int k = 0; k < GR_CHUNK; ++k) {
    f32x4 a0 = *(f32x4*)&Ws[k * 128 + 8 * tr];
    f32x4 a1 = *(f32x4*)&Ws[k * 128 + 8 * tr + 4];
    f32x4 b0 = *(f32x4*)&Ws[k * 128 + 8 * tc];
    f32x4 b1 = *(f32x4*)&Ws[k * 128 + 8 * tc + 4];
    float av[8] = {a0.x, a0.y, a0.z, a0.w, a1.x, a1.y, a1.z, a1.w};
    float bv[8] = {b0.x, b0.y, b0.z, b0.w, b1.x, b1.y, b1.z, b1.w};
#pragma unroll
    for (int r = 0; r < 8; ++r)
#pragma unroll
      for (int c = 0; c < 8; ++c) acc[r][c] = fmaf(av[r], bv[c], acc[r][c]);
  }
  float* dst = M + (size_t)(8 * tr) * 128 + 8 * tc;
#pragma unroll
  for (int r = 0; r < 8; ++r)
#pragma unroll
    for (int c = 0; c < 8; ++c) atomicAdd(&dst[r * 128 + c], acc[r][c]);
  // Wt conversion: thread -> (col n, 32-k half)
  int n = t >> 1, h = t & 1;
  unsigned pk[16];
#pragma unroll
  for (int c = 0; c < 16; ++c)
    pk[c] = (unsigned)f2bf(Ws[(h * 32 + 2 * c) * 128 + n]) |
            ((unsigned)f2bf(Ws[(h * 32 + 2 * c + 1) * 128 + n]) << 16);
  uint4* wd = (uint4*)(Wt + (size_t)n * N_FEAT + k0 + h * 32);
#pragma unroll
  for (int c = 0; c < 4; ++c)
    wd[c] = make_uint4(pk[4 * c], pk[4 * c + 1], pk[4 * c + 2], pk[4 * c + 3]);
  // tmu partials + ||mean||^2 partial
  if (t < 128) {
    float tm = 0.f;
#pragma unroll 8
    for (int k = 0; k < GR_CHUNK; ++k)
      tm = fmaf(Ws[k * 128 + t], mean[k0 + k], tm);
    atomicAdd(&tmu[t], tm);
  } else if (t == 128) {
    float s = 0.f;
#pragma unroll 8
    for (int k = 0; k < GR_CHUNK; ++k) {
      float m = mean[k0 + k];
      s = fmaf(m, m, s);
    }
    atomicAdd(&scal[2], s);
  }
}

// ---------------------------------------------------------------------------
// k_inv: register-tile Gauss-Jordan inverse of M + sigma^2 I; logdet; scalars.
// Standalone again so its true cost shows in the profile.
// ---------------------------------------------------------------------------
__global__ __launch_bounds__(256) void k_inv(float* __restrict__ M,
                                             float* __restrict__ scal,
                                             const float* __restrict__ log_var) {
  __shared__ float prow[2][128];
  __shared__ float pcol[2][128];
  __shared__ float dbuf[2];
  __shared__ float diag[128];
  __shared__ float red[2];
  int t = threadIdx.x;
  int tr = t >> 4, tc = t & 15;
  float lv = log_var[0];
  float sig2 = expf(lv);
  float a[8][8];
  const float* src = M + (size_t)(8 * tr) * 128 + 8 * tc;
#pragma unroll
  for (int r = 0; r < 8; ++r) {
    f32x4 v0 = *(const f32x4*)(src + r * 128);
    f32x4 v1 = *(const f32x4*)(src + r * 128 + 4);
    a[r][0] = v0.x; a[r][1] = v0.y; a[r][2] = v0.z; a[r][3] = v0.w;
    a[r][4] = v1.x; a[r][5] = v1.y; a[r][6] = v1.z; a[r][7] = v1.w;
  }
  if (tr == tc) {
#pragma unroll
    for (int r = 0; r < 8; ++r) a[r][r] += sig2;
  }
  if (tr == 0) {
#pragma unroll
    for (int c = 0; c < 8; ++c) prow[0][8 * tc + c] = a[0][c];
  }
  if (tc == 0) {
#pragma unroll
    for (int r = 0; r < 8; ++r) pcol[0][8 * tr + r] = a[r][0];
  }
  if (t == 0) dbuf[0] = a[0][0];
  __syncthreads();

  for (int kb = 0; kb < 16; ++kb) {
#pragma unroll
    for (int lk = 0; lk < 8; ++lk) {
      const int k = kb * 8 + lk;
      const int buf = k & 1;
      float d = dbuf[buf];
      if (t == 0) diag[k] = d;
      float p = 1.0f / d;
      float pr[8], pc[8];
#pragma unroll
      for (int c = 0; c < 8; ++c) pr[c] = prow[buf][8 * tc + c] * p;
#pragma unroll
      for (int r = 0; r < 8; ++r) pc[r] = pcol[buf][8 * tr + r];
#pragma unroll
      for (int r = 0; r < 8; ++r)
#pragma unroll
        for (int c = 0; c < 8; ++c) a[r][c] = fmaf(-pc[r], pr[c], a[r][c]);
      bool myrow = (tr == (k >> 3));
      bool mycol = (tc == (k >> 3));
      if (myrow) {
#pragma unroll
        for (int c = 0; c < 8; ++c) a[lk][c] = pr[c];
      }
      if (mycol) {
#pragma unroll
        for (int r = 0; r < 8; ++r) a[r][lk] = -p * pc[r];
      }
      if (myrow && mycol) a[lk][lk] = p;
      if (k + 1 < 128) {
        const int nb = buf ^ 1;
        const int nl = (lk + 1) & 7;
        const int nr = (k + 1) >> 3;
        if (tr == nr) {
#pragma unroll
          for (int c = 0; c < 8; ++c) prow[nb][8 * tc + c] = a[nl][c];
        }
        if (tc == nr) {
#pragma unroll
          for (int r = 0; r < 8; ++r) pcol[nb][8 * tr + r] = a[r][nl];
        }
        if (tr == nr && tc == nr) dbuf[nb] = a[nl][nl];
      }
      __syncthreads();
    }
  }

  float* dst = M + (size_t)(8 * tr) * 128 + 8 * tc;
#pragma unroll
  for (int r = 0; r < 8; ++r) {
    f32x4 v0 = {a[r][0], a[r][1], a[r][2], a[r][3]};
    f32x4 v1 = {a[r][4], a[r][5], a[r][6], a[r][7]};
    *(f32x4*)(dst + r * 128) = v0;
    *(f32x4*)(dst + r * 128 + 4) = v1;
  }
  float ld = 0.f;
  if (t < 128) ld = logf(diag[t]);
#pragma unroll
  for (int o = 1; o < 64; o <<= 1) ld += __shfl_xor(ld, o);
  if (t == 0) red[0] = ld;
  if (t == 64) red[1] = ld;
  __syncthreads();
  if (t == 0) {
    scal[0] = -0.5f * (N_FEAT * LOG2PI + (float)(N_FEAT - LATENT) * lv +
                       (red[0] + red[1]));
    scal[1] = expf(-lv);
  }
}

// ---------------------------------------------------------------------------
// k_gemm v3: T = Xb * Wt^T via m97-style K-loop: global_load_lds 16B DMA for
// both tiles, BK=128, double-buffered, 1 barrier/chunk, no atomics.
// Global-side XOR swizzle (lane fetches chunk lk^(row&7)) kills the 16-way
// frag-read bank aliasing that a raw [row][128] layout would have.
// 256 blocks x 512 thr; wave = 16 rows x 32 cols.
// ---------------------------------------------------------------------------
__global__ __launch_bounds__(512) void k_gemm(const unsigned short* __restrict__ Xb,
                                              const unsigned short* __restrict__ Wt,
                                              float* __restrict__ T) {
  __shared__ __align__(16) unsigned short As[2][32][128];
  __shared__ __align__(16) unsigned short Bs[2][128][128];
  int t = threadIdx.x;
  int l = t & 63, w = t >> 6;
  int wr = w & 1, wc = w >> 1;
  int fr = l & 15, fq = l >> 4;
  int r0 = blockIdx.x * 32;
  int lr = l >> 4, lk = l & 15;

  // DMA source/dest: wave w covers As rows 4w..4w+3; Bs rows 4w+32i..+3
  int arow = 4 * w + lr;
  const unsigned short* ga =
      Xb + (size_t)(r0 + arow) * N_FEAT + (lk ^ (arow & 7)) * 8;
  unsigned short* la = &As[0][4 * w][0];
  const unsigned short* gb[4];
  unsigned short* lb[4];
#pragma unroll
  for (int i = 0; i < 4; ++i) {
    int br = 4 * w + 32 * i + lr;
    gb[i] = Wt + (size_t)br * N_FEAT + (lk ^ (br & 7)) * 8;
    lb[i] = &Bs[0][4 * w + 32 * i][0];
  }

  // prologue: chunk 0 -> buf 0
  GLL(ga, la);
#pragma unroll
  for (int i = 0; i < 4; ++i) GLL(gb[i], lb[i]);

  int ar = wr * 16 + fr;
  int arm = ar & 7;
  int n0 = wc * 32 + fr, n1 = n0 + 16;
  int nm0 = n0 & 7, nm1 = n1 & 7;
  const unsigned short* Ab = &As[0][ar][0];
  const unsigned short* Bb0 = &Bs[0][n0][0];
  const unsigned short* Bb1 = &Bs[0][n1][0];

  f32x4 acc0 = {0.f, 0.f, 0.f, 0.f}, acc1 = {0.f, 0.f, 0.f, 0.f};

  for (int it = 0; it < 24; ++it) {
    const int buf = it & 1;
    __syncthreads();
    if (it + 1 < 24) {
      const int nb = buf ^ 1;
      GLL(ga + (size_t)(it + 1) * 128, la + nb * 4096);
#pragma unroll
      for (int i = 0; i < 4; ++i)
        GLL(gb[i] + (size_t)(it + 1) * 128, lb[i] + nb * 16384);
    }
    const unsigned short* ab = Ab + buf * 4096;
    const unsigned short* b0p = Bb0 + buf * 16384;
    const unsigned short* b1p = Bb1 + buf * 16384;
#pragma unroll
    for (int ks = 0; ks < 4; ++ks) {
      short8 a = *(const short8*)(ab + ((((ks << 2) | fq) ^ arm) << 3));
      short8 b0 = *(const short8*)(b0p + ((((ks << 2) | fq) ^ nm0) << 3));
      short8 b1 = *(const short8*)(b1p + ((((ks << 2) | fq) ^ nm1) << 3));
      acc0 = __builtin_amdgcn_mfma_f32_16x16x32_bf16(a, b0, acc0, 0, 0, 0);
      acc1 = __builtin_amdgcn_mfma_f32_16x16x32_bf16(a, b1, acc1, 0, 0, 0);
    }
  }

  // D layout: col = fr, row = fq*4 + ii
  float* tp = T + (size_t)(r0 + wr * 16 + fq * 4) * 128 + wc * 32 + fr;
#pragma unroll
  for (int ii = 0; ii < 4; ++ii) {
    tp[(size_t)ii * 128] = acc0[ii];
    tp[(size_t)ii * 128 + 16] = acc1[ii];
  }
}

// ---------------------------------------------------------------------------
// k_epi: t = tx - tmu; q = t^T Minv t; rs = ssq - 2 xmu + ||mu||^2;
// out = scal0 - 0.5*scal1*(rs - q).
// ---------------------------------------------------------------------------
__global__ __launch_bounds__(256) void k_epi(const float* __restrict__ T,
                                             const float* __restrict__ ssq,
                                             const float* __restrict__ xmu,
                                             const float* __restrict__ tmu,
                                             const float* __restrict__ Minv,
                                             const float* __restrict__ scal,
                                             float* __restrict__ out) {
  __shared__ __align__(16) float Ts[32][132];
  __shared__ float rs[32];
  int t = threadIdx.x;
  int r0 = blockIdx.x * 32;
  int sr = t >> 3, sseg = t & 7;
  const float* tp = T + (size_t)(r0 + sr) * 128 + sseg * 16;
#pragma unroll
  for (int c = 0; c < 4; ++c) {
    float4 v = *(const float4*)(tp + c * 4);
    float4 u = *(const float4*)(tmu + sseg * 16 + c * 4);
    Ts[sr][sseg * 16 + c * 4 + 0] = v.x - u.x;
    Ts[sr][sseg * 16 + c * 4 + 1] = v.y - u.y;
    Ts[sr][sseg * 16 + c * 4 + 2] = v.z - u.z;
    Ts[sr][sseg * 16 + c * 4 + 3] = v.w - u.w;
  }
  if (t < 32) rs[t] = ssq[r0 + t] - 2.f * xmu[r0 + t] + scal[2];
  __syncthreads();

  int rp = t >> 4, cg = t & 15;
  int ra = 2 * rp, rb = ra + 1;
  int c0 = cg * 8;
  float ya[8] = {0, 0, 0, 0, 0, 0, 0, 0};
  float yb[8] = {0, 0, 0, 0, 0, 0, 0, 0};
#pragma unroll 4
  for (int j = 0; j < 128; ++j) {
    float tav = Ts[ra][j];
    float tbv = Ts[rb][j];
    float4 v0 = *(const float4*)(Minv + j * LATENT + c0);
    float4 v1 = *(const float4*)(Minv + j * LATENT + c0 + 4);
    ya[0] = fmaf(tav, v0.x, ya[0]); ya[1] = fmaf(tav, v0.y, ya[1]);
    ya[2] = fmaf(tav, v0.z, ya[2]); ya[3] = fmaf(tav, v0.w, ya[3]);
    ya[4] = fmaf(tav, v1.x, ya[4]); ya[5] = fmaf(tav, v1.y, ya[5]);
    ya[6] = fmaf(tav, v1.z, ya[6]); ya[7] = fmaf(tav, v1.w, ya[7]);
    yb[0] = fmaf(tbv, v0.x, yb[0]); yb[1] = fmaf(tbv, v0.y, yb[1]);
    yb[2] = fmaf(tbv, v0.z, yb[2]); yb[3] = fmaf(tbv, v0.w, yb[3]);
    yb[4] = fmaf(tbv, v1.x, yb[4]); yb[5] = fmaf(tbv, v1.y, yb[5]);
    yb[6] = fmaf(tbv, v1.z, yb[6]); yb[7] = fmaf(tbv, v1.w, yb[7]);
  }
  float q0 = 0.f, q1 = 0.f;
#pragma unroll
  for (int c = 0; c < 8; ++c) {
    q0 = fmaf(ya[c], Ts[ra][c0 + c], q0);
    q1 = fmaf(yb[c], Ts[rb][c0 + c], q1);
  }
  q0 += __shfl_xor(q0, 1); q0 += __shfl_xor(q0, 2);
  q0 += __shfl_xor(q0, 4); q0 += __shfl_xor(q0, 8);
  q1 += __shfl_xor(q1, 1); q1 += __shfl_xor(q1, 2);
  q1 += __shfl_xor(q1, 4); q1 += __shfl_xor(q1, 8);
  if (cg == 0) {
    float cc = scal[0], is2 = scal[1];
    out[r0 + ra] = cc - 0.5f * is2 * (rs[ra] - q0);
    out[r0 + rb] = cc - 0.5f * is2 * (rs[rb] - q1);
  }
}

// ---------------------------------------------------------------------------
extern "C" void kernel_launch(void* const* d_in, const int* in_sizes, int n_in,
                              void* d_out, int out_size, void* d_ws, size_t ws_size,
                              hipStream_t stream) {
  (void)in_sizes; (void)n_in; (void)out_size; (void)ws_size;
  const float* ex   = (const float*)d_in[0];
  const float* W    = (const float*)d_in[1];
  const float* lv   = (const float*)d_in[2];
  const float* mean = (const float*)d_in[3];
  float* out = (float*)d_out;

  // ws layout (floats): M 16384 | scal 64 | tmu 128 | ssq 8192 | xmu 8192 |
  //                     T 1048576 | then Wt (128*3072 bf16) | Xb (8192*3072 bf16)
  float* M = (float*)d_ws;
  float* scal = M + 16384;
  float* tmu = scal + 64;
  float* ssq = tmu + 128;
  float* xmu = ssq + 8192;
  float* T = xmu + 8192;
  unsigned short* Wt = (unsigned short*)(T + 1048576);
  unsigned short* Xb = Wt + (size_t)128 * N_FEAT;

  // zero only atomic-accumulated regions: M, scal, tmu
  hipMemsetAsync(M, 0, (size_t)(16384 + 64 + 128) * sizeof(float), stream);
  k_pack<<<2048, 256, 0, stream>>>(ex, mean, Xb, ssq, xmu);
  k_prep<<<48, 256, 0, stream>>>(W, mean, M, Wt, tmu, scal);
  k_inv<<<1, 256, 0, stream>>>(M, scal, lv);
  k_gemm<<<256, 512, 0, stream>>>(Xb, Wt, T);
  k_epi<<<256, 256, 0, stream>>>(T, ssq, xmu, tmu, M, scal, out);
}

// Round 5
// 282.835 us; speedup vs baseline: 1.0335x; 1.0335x over previous
//
#include <hip/hip_runtime.h>
#include <hip/hip_bf16.h>

#define N_FEAT 3072
#define LATENT 128
#define LOG2PI 1.8378770664093453f

typedef __attribute__((ext_vector_type(8))) short short8;
typedef __attribute__((ext_vector_type(4))) float f32x4;

__device__ __forceinline__ unsigned short f2bf(float x) {
  unsigned int u = __float_as_uint(x);
  u += 0x7FFFu + ((u >> 16) & 1u);
  return (unsigned short)(u >> 16);
}

// async global->LDS DMA, 16B per lane; lds base must be wave-uniform
#define GLL(g, l)                                                        \
  __builtin_amdgcn_global_load_lds(                                      \
      (__attribute__((address_space(1))) void*)(g),                      \
      (__attribute__((address_space(3))) void*)(l), 16, 0, 0)

// ---------------------------------------------------------------------------
// k_prep: (a) M += Wchunk^T Wchunk (atomics, M pre-zeroed)
//         (b) Wt[n][k] = bf16(W[k][n])
//         (c) tmu[j] += sum_k W[k][j]*mean[k];  scal[2] += sum mean^2
// 48 blocks x 64 k-rows; W read once.  (proven round 4)
// ---------------------------------------------------------------------------
#define GR_CHUNK 64
__global__ __launch_bounds__(256) void k_prep(const float* __restrict__ W,
                                              const float* __restrict__ mean,
                                              float* __restrict__ M,
                                              unsigned short* __restrict__ Wt,
                                              float* __restrict__ tmu,
                                              float* __restrict__ scal) {
  __shared__ __align__(16) float Ws[GR_CHUNK * 128];
  int t = threadIdx.x;
  int k0 = blockIdx.x * GR_CHUNK;
  const float* src = W + (size_t)k0 * 128;
#pragma unroll
  for (int c = 0; c < 8; ++c)
    ((float4*)Ws)[t + 256 * c] = ((const float4*)src)[t + 256 * c];
  __syncthreads();
  int tr = t >> 4, tc = t & 15;
  float acc[8][8];
#pragma unroll
  for (int r = 0; r < 8; ++r)
#pragma unroll
    for (int c = 0; c < 8; ++c) acc[r][c] = 0.f;
#pragma unroll 2
  for (int k = 0; k < GR_CHUNK; ++k) {
    f32x4 a0 = *(f32x4*)&Ws[k * 128 + 8 * tr];
    f32x4 a1 = *(f32x4*)&Ws[k * 128 + 8 * tr + 4];
    f32x4 b0 = *(f32x4*)&Ws[k * 128 + 8 * tc];
    f32x4 b1 = *(f32x4*)&Ws[k * 128 + 8 * tc + 4];
    float av[8] = {a0.x, a0.y, a0.z, a0.w, a1.x, a1.y, a1.z, a1.w};
    float bv[8] = {b0.x, b0.y, b0.z, b0.w, b1.x, b1.y, b1.z, b1.w};
#pragma unroll
    for (int r = 0; r < 8; ++r)
#pragma unroll
      for (int c = 0; c < 8; ++c) acc[r][c] = fmaf(av[r], bv[c], acc[r][c]);
  }
  float* dst = M + (size_t)(8 * tr) * 128 + 8 * tc;
#pragma unroll
  for (int r = 0; r < 8; ++r)
#pragma unroll
    for (int c = 0; c < 8; ++c) atomicAdd(&dst[r * 128 + c], acc[r][c]);
  int n = t >> 1, h = t & 1;
  unsigned pk[16];
#pragma unroll
  for (int c = 0; c < 16; ++c)
    pk[c] = (unsigned)f2bf(Ws[(h * 32 + 2 * c) * 128 + n]) |
            ((unsigned)f2bf(Ws[(h * 32 + 2 * c + 1) * 128 + n]) << 16);
  uint4* wd = (uint4*)(Wt + (size_t)n * N_FEAT + k0 + h * 32);
#pragma unroll
  for (int c = 0; c < 4; ++c)
    wd[c] = make_uint4(pk[4 * c], pk[4 * c + 1], pk[4 * c + 2], pk[4 * c + 3]);
  if (t < 128) {
    float tm = 0.f;
#pragma unroll 8
    for (int k = 0; k < GR_CHUNK; ++k)
      tm = fmaf(Ws[k * 128 + t], mean[k0 + k], tm);
    atomicAdd(&tmu[t], tm);
  } else if (t == 128) {
    float s = 0.f;
#pragma unroll 8
    for (int k = 0; k < GR_CHUNK; ++k) {
      float m = mean[k0 + k];
      s = fmaf(m, m, s);
    }
    atomicAdd(&scal[2], s);
  }
}

// ---------------------------------------------------------------------------
// k_packinv: blocks 0..2047: Xb = bf16(x); ssq[r]=||x||^2; xmu[r]=x.mean
//            block 2048:     register-tile Gauss-Jordan inverse of
//                            M + sigma^2 I (in-place), logdet, scalars.
// The inv block runs CONCURRENTLY with the streaming pack blocks (hidden).
// ---------------------------------------------------------------------------
__global__ __launch_bounds__(256) void k_packinv(const float* __restrict__ ex,
                                                 const float* __restrict__ mean,
                                                 unsigned short* __restrict__ Xb,
                                                 float* __restrict__ ssq,
                                                 float* __restrict__ xmu,
                                                 float* __restrict__ M,
                                                 float* __restrict__ scal,
                                                 const float* __restrict__ log_var) {
  int t = threadIdx.x;
  if (blockIdx.x == 2048) {
    // ---------------- inverse path ----------------
    __shared__ float prow[2][128];
    __shared__ float pcol[2][128];
    __shared__ float dbuf[2];
    __shared__ float diag[128];
    __shared__ float red[2];
    int tr = t >> 4, tc = t & 15;
    float lv = log_var[0];
    float sig2 = expf(lv);
    float a[8][8];
    const float* src = M + (size_t)(8 * tr) * 128 + 8 * tc;
#pragma unroll
    for (int r = 0; r < 8; ++r) {
      f32x4 v0 = *(const f32x4*)(src + r * 128);
      f32x4 v1 = *(const f32x4*)(src + r * 128 + 4);
      a[r][0] = v0.x; a[r][1] = v0.y; a[r][2] = v0.z; a[r][3] = v0.w;
      a[r][4] = v1.x; a[r][5] = v1.y; a[r][6] = v1.z; a[r][7] = v1.w;
    }
    if (tr == tc) {
#pragma unroll
      for (int r = 0; r < 8; ++r) a[r][r] += sig2;
    }
    if (tr == 0) {
#pragma unroll
      for (int c = 0; c < 8; ++c) prow[0][8 * tc + c] = a[0][c];
    }
    if (tc == 0) {
#pragma unroll
      for (int r = 0; r < 8; ++r) pcol[0][8 * tr + r] = a[r][0];
    }
    if (t == 0) dbuf[0] = a[0][0];
    __syncthreads();

    for (int kb = 0; kb < 16; ++kb) {
#pragma unroll
      for (int lk = 0; lk < 8; ++lk) {
        const int k = kb * 8 + lk;
        const int buf = k & 1;
        float d = dbuf[buf];
        if (t == 0) diag[k] = d;
        float p = 1.0f / d;
        float pr[8], pc[8];
#pragma unroll
        for (int c = 0; c < 8; ++c) pr[c] = prow[buf][8 * tc + c] * p;
#pragma unroll
        for (int r = 0; r < 8; ++r) pc[r] = pcol[buf][8 * tr + r];
#pragma unroll
        for (int r = 0; r < 8; ++r)
#pragma unroll
          for (int c = 0; c < 8; ++c) a[r][c] = fmaf(-pc[r], pr[c], a[r][c]);
        bool myrow = (tr == (k >> 3));
        bool mycol = (tc == (k >> 3));
        if (myrow) {
#pragma unroll
          for (int c = 0; c < 8; ++c) a[lk][c] = pr[c];
        }
        if (mycol) {
#pragma unroll
          for (int r = 0; r < 8; ++r) a[r][lk] = -p * pc[r];
        }
        if (myrow && mycol) a[lk][lk] = p;
        if (k + 1 < 128) {
          const int nb = buf ^ 1;
          const int nl = (lk + 1) & 7;
          const int nr = (k + 1) >> 3;
          if (tr == nr) {
#pragma unroll
            for (int c = 0; c < 8; ++c) prow[nb][8 * tc + c] = a[nl][c];
          }
          if (tc == nr) {
#pragma unroll
            for (int r = 0; r < 8; ++r) pcol[nb][8 * tr + r] = a[r][nl];
          }
          if (tr == nr && tc == nr) dbuf[nb] = a[nl][nl];
        }
        __syncthreads();
      }
    }

    float* dst = M + (size_t)(8 * tr) * 128 + 8 * tc;
#pragma unroll
    for (int r = 0; r < 8; ++r) {
      f32x4 v0 = {a[r][0], a[r][1], a[r][2], a[r][3]};
      f32x4 v1 = {a[r][4], a[r][5], a[r][6], a[r][7]};
      *(f32x4*)(dst + r * 128) = v0;
      *(f32x4*)(dst + r * 128 + 4) = v1;
    }
    float ld = 0.f;
    if (t < 128) ld = logf(diag[t]);
#pragma unroll
    for (int o = 1; o < 64; o <<= 1) ld += __shfl_xor(ld, o);
    if (t == 0) red[0] = ld;
    if (t == 64) red[1] = ld;
    __syncthreads();
    if (t == 0) {
      scal[0] = -0.5f * (N_FEAT * LOG2PI + (float)(N_FEAT - LATENT) * lv +
                         (red[0] + red[1]));
      scal[1] = expf(-lv);
    }
    return;
  }

  // ---------------- pack path (streaming, barrier-free) ----------------
  int w = t >> 6, l = t & 63;
  int row = blockIdx.x * 4 + w;
  const float* xp = ex + (size_t)row * N_FEAT;
  unsigned short* op = Xb + (size_t)row * N_FEAT;
  float sq = 0.f, dm = 0.f;
#pragma unroll
  for (int c = 0; c < 6; ++c) {
    int off = c * 512 + l * 8;
    float4 x0 = *(const float4*)(xp + off);
    float4 x1 = *(const float4*)(xp + off + 4);
    float4 m0 = *(const float4*)(mean + off);
    float4 m1 = *(const float4*)(mean + off + 4);
    sq = fmaf(x0.x, x0.x, sq); sq = fmaf(x0.y, x0.y, sq);
    sq = fmaf(x0.z, x0.z, sq); sq = fmaf(x0.w, x0.w, sq);
    sq = fmaf(x1.x, x1.x, sq); sq = fmaf(x1.y, x1.y, sq);
    sq = fmaf(x1.z, x1.z, sq); sq = fmaf(x1.w, x1.w, sq);
    dm = fmaf(x0.x, m0.x, dm); dm = fmaf(x0.y, m0.y, dm);
    dm = fmaf(x0.z, m0.z, dm); dm = fmaf(x0.w, m0.w, dm);
    dm = fmaf(x1.x, m1.x, dm); dm = fmaf(x1.y, m1.y, dm);
    dm = fmaf(x1.z, m1.z, dm); dm = fmaf(x1.w, m1.w, dm);
    uint4 pk;
    pk.x = (unsigned)f2bf(x0.x) | ((unsigned)f2bf(x0.y) << 16);
    pk.y = (unsigned)f2bf(x0.z) | ((unsigned)f2bf(x0.w) << 16);
    pk.z = (unsigned)f2bf(x1.x) | ((unsigned)f2bf(x1.y) << 16);
    pk.w = (unsigned)f2bf(x1.z) | ((unsigned)f2bf(x1.w) << 16);
    *(uint4*)(op + off) = pk;
  }
#pragma unroll
  for (int o = 1; o < 64; o <<= 1) {
    sq += __shfl_xor(sq, o);
    dm += __shfl_xor(dm, o);
  }
  if (l == 0) {
    ssq[row] = sq;
    xmu[row] = dm;
  }
}

// ---------------------------------------------------------------------------
// k_gemm: T-tile = Xb * Wt^T (m97-style DMA K-loop, proven round 4) with the
// quadratic-form epilogue FUSED: acc spills to LDS (minus tmu), then
// q = t^T Minv t, out = scal0 - 0.5*scal1*(ssq - 2 xmu + ||mu||^2 - q).
// 256 blocks x 512 thr; block = 32 rows x 128 cols.
// ---------------------------------------------------------------------------
__global__ __launch_bounds__(512) void k_gemm(const unsigned short* __restrict__ Xb,
                                              const unsigned short* __restrict__ Wt,
                                              const float* __restrict__ Minv,
                                              const float* __restrict__ ssq,
                                              const float* __restrict__ xmu,
                                              const float* __restrict__ tmu,
                                              const float* __restrict__ scal,
                                              float* __restrict__ out) {
  __shared__ __align__(16) unsigned short As[2][32][128];
  __shared__ __align__(16) unsigned short Bs[2][128][128];
  __shared__ __align__(16) float Ts[32][132];
  __shared__ float tm[128];
  __shared__ float rs[32];
  int t = threadIdx.x;
  int l = t & 63, w = t >> 6;
  int wr = w & 1, wc = w >> 1;
  int fr = l & 15, fq = l >> 4;
  int r0 = blockIdx.x * 32;
  int lr = l >> 4, lk = l & 15;

  if (t < 128) tm[t] = tmu[t];

  int arow = 4 * w + lr;
  const unsigned short* ga =
      Xb + (size_t)(r0 + arow) * N_FEAT + (lk ^ (arow & 7)) * 8;
  unsigned short* la = &As[0][4 * w][0];
  const unsigned short* gb[4];
  unsigned short* lb[4];
#pragma unroll
  for (int i = 0; i < 4; ++i) {
    int br = 4 * w + 32 * i + lr;
    gb[i] = Wt + (size_t)br * N_FEAT + (lk ^ (br & 7)) * 8;
    lb[i] = &Bs[0][4 * w + 32 * i][0];
  }

  // prologue: chunk 0 -> buf 0
  GLL(ga, la);
#pragma unroll
  for (int i = 0; i < 4; ++i) GLL(gb[i], lb[i]);

  int ar = wr * 16 + fr;
  int arm = ar & 7;
  int n0 = wc * 32 + fr, n1 = n0 + 16;
  int nm0 = n0 & 7, nm1 = n1 & 7;
  const unsigned short* Ab = &As[0][ar][0];
  const unsigned short* Bb0 = &Bs[0][n0][0];
  const unsigned short* Bb1 = &Bs[0][n1][0];

  f32x4 acc0 = {0.f, 0.f, 0.f, 0.f}, acc1 = {0.f, 0.f, 0.f, 0.f};

  for (int it = 0; it < 24; ++it) {
    const int buf = it & 1;
    __syncthreads();
    if (it + 1 < 24) {
      const int nb = buf ^ 1;
      GLL(ga + (size_t)(it + 1) * 128, la + nb * 4096);
#pragma unroll
      for (int i = 0; i < 4; ++i)
        GLL(gb[i] + (size_t)(it + 1) * 128, lb[i] + nb * 16384);
    }
    const unsigned short* ab = Ab + buf * 4096;
    const unsigned short* b0p = Bb0 + buf * 16384;
    const unsigned short* b1p = Bb1 + buf * 16384;
#pragma unroll
    for (int ks = 0; ks < 4; ++ks) {
      short8 a = *(const short8*)(ab + ((((ks << 2) | fq) ^ arm) << 3));
      short8 b0 = *(const short8*)(b0p + ((((ks << 2) | fq) ^ nm0) << 3));
      short8 b1 = *(const short8*)(b1p + ((((ks << 2) | fq) ^ nm1) << 3));
      acc0 = __builtin_amdgcn_mfma_f32_16x16x32_bf16(a, b0, acc0, 0, 0, 0);
      acc1 = __builtin_amdgcn_mfma_f32_16x16x32_bf16(a, b1, acc1, 0, 0, 0);
    }
  }

  // ---- spill T-tile to LDS with tmu subtracted ----
  // D layout: col = fr, row = fq*4 + ii
  __syncthreads();   // last MFMA buffer reads done; safe to reuse nothing, but
                     // needed so all waves' tm[] stage (t<128) is visible too
  {
    float u0 = tm[wc * 32 + fr];
    float u1 = tm[wc * 32 + fr + 16];
#pragma unroll
    for (int ii = 0; ii < 4; ++ii) {
      Ts[wr * 16 + fq * 4 + ii][wc * 32 + fr] = acc0[ii] - u0;
      Ts[wr * 16 + fq * 4 + ii][wc * 32 + fr + 16] = acc1[ii] - u1;
    }
  }
  if (t < 32) rs[t] = ssq[r0 + t] - 2.f * xmu[r0 + t] + scal[2];
  __syncthreads();

  // ---- epilogue: row = t>>4 (0..31), 16 threads/row x 8 cols ----
  int row = t >> 4, cg = t & 15;
  int c0 = cg * 8;
  float y[8] = {0, 0, 0, 0, 0, 0, 0, 0};
#pragma unroll 4
  for (int j = 0; j < 128; ++j) {
    float tv = Ts[row][j];
    float4 v0 = *(const float4*)(Minv + j * LATENT + c0);
    float4 v1 = *(const float4*)(Minv + j * LATENT + c0 + 4);
    y[0] = fmaf(tv, v0.x, y[0]); y[1] = fmaf(tv, v0.y, y[1]);
    y[2] = fmaf(tv, v0.z, y[2]); y[3] = fmaf(tv, v0.w, y[3]);
    y[4] = fmaf(tv, v1.x, y[4]); y[5] = fmaf(tv, v1.y, y[5]);
    y[6] = fmaf(tv, v1.z, y[6]); y[7] = fmaf(tv, v1.w, y[7]);
  }
  float q = 0.f;
#pragma unroll
  for (int c = 0; c < 8; ++c) q = fmaf(y[c], Ts[row][c0 + c], q);
  q += __shfl_xor(q, 1); q += __shfl_xor(q, 2);
  q += __shfl_xor(q, 4); q += __shfl_xor(q, 8);
  if (cg == 0)
    out[r0 + row] = scal[0] - 0.5f * scal[1] * (rs[row] - q);
}

// ---------------------------------------------------------------------------
extern "C" void kernel_launch(void* const* d_in, const int* in_sizes, int n_in,
                              void* d_out, int out_size, void* d_ws, size_t ws_size,
                              hipStream_t stream) {
  (void)in_sizes; (void)n_in; (void)out_size; (void)ws_size;
  const float* ex   = (const float*)d_in[0];
  const float* W    = (const float*)d_in[1];
  const float* lv   = (const float*)d_in[2];
  const float* mean = (const float*)d_in[3];
  float* out = (float*)d_out;

  // ws layout (floats): M 16384 | scal 64 | tmu 128 | ssq 8192 | xmu 8192 |
  //                     then Wt (128*3072 bf16) | Xb (8192*3072 bf16)
  float* M = (float*)d_ws;
  float* scal = M + 16384;
  float* tmu = scal + 64;
  float* ssq = tmu + 128;
  float* xmu = ssq + 8192;
  unsigned short* Wt = (unsigned short*)(xmu + 8192);
  unsigned short* Xb = Wt + (size_t)128 * N_FEAT;

  // zero only atomic-accumulated regions: M, scal, tmu
  hipMemsetAsync(M, 0, (size_t)(16384 + 64 + 128) * sizeof(float), stream);
  k_prep<<<48, 256, 0, stream>>>(W, mean, M, Wt, tmu, scal);
  k_packinv<<<2049, 256, 0, stream>>>(ex, mean, Xb, ssq, xmu, M, scal, lv);
  k_gemm<<<256, 512, 0, stream>>>(Xb, Wt, M, ssq, xmu, tmu, scal, out);
}